// Round 5
// baseline (168.327 us; speedup 1.0000x reference)
//
#include <hip/hip_runtime.h>

// Problem constants (from reference)
#define BQ 2
#define HQ 16
#define SQ 8192
#define DQ 128
#define STR 16
#define NWIN 511     // (8192-32)/16 + 1
#define NBLK 512     // NWIN + 1 zero block
#define WPB 8        // windows per workgroup
#define NWG_PER_HEAD 64

typedef float f32x4 __attribute__((ext_vector_type(4)));
typedef short s16x8 __attribute__((ext_vector_type(8)));

// LDS 68 KB map (regions reused as the pyramid shrinks; all bases 4096-aligned
// so the swizzle key (byte bits 9-11) is unperturbed):
//   kin   @0      36864B (144 rows x 256B: 8 overlapping windows loaded once)
//   s0out @36864  32768B (128 rows x 256B)
//   s1out @0      16 KB (64 rows)    -- kin dead after stage 0
//   s2out @36864   8 KB (32 rows)    -- s0out dead after stage 1
//   s3out @0       4 KB (16 rows)    -- s1out dead
//   s4out @40960   2 KB (8 rows)     -- inside dead s2out region
#define R_KIN 0u
#define R_S0  36864u
#define R_S1  0u
#define R_S2  36864u
#define R_S3  0u
#define R_S4  40960u

// XOR swizzle keyed on 512B granule (G4/T2). Involution on global LDS byte
// offsets; writers and readers apply it to the same global byte -> consistent.
static __device__ __forceinline__ unsigned swz(unsigned b) {
    return b ^ (((b >> 9) & 7u) << 4);
}

static __device__ __forceinline__ short f2bf(float f) {
    __bf16 h = (__bf16)f;
    return __builtin_bit_cast(short, h);
}

static __device__ __forceinline__ float silu(float v) {
    return v / (1.f + __expf(-v));
}

// ---- pass 0a: convert weights f32 -> bf16 into workspace ----
// ws layout: wd_bf[5][128][256] (163840 sh) + wstop_bf[128][128] (16384 sh)
//            + bias0 f32[16][128] at byte 360448
__global__ void convw_kernel(const float* __restrict__ wd,
                             const float* __restrict__ wstop,
                             short* __restrict__ o) {
    int i = blockIdx.x * 256 + threadIdx.x;
    if (i < 163840) {
        o[i] = f2bf(wd[i]);
    } else if (i < 180224) {
        o[i] = f2bf(wstop[i - 163840]);
    }
}

// ---- pass 0b: bias0[j][c] = sum_i W0[c][i] * concat(pe[2j],pe[2j+1])[i] ----
__global__ void bias0_kernel(const float* __restrict__ wd,
                             const float* __restrict__ pe,
                             float* __restrict__ bias) {
    int o = blockIdx.x * 256 + threadIdx.x;   // 0..2047
    int j = o >> 7;
    int c = o & 127;
    const float* w  = wd + (size_t)c * 256;
    const float* p0 = pe + (2 * j) * DQ;
    const float* p1 = pe + (2 * j + 1) * DQ;
    float s = 0.f;
    #pragma unroll 4
    for (int i = 0; i < 128; ++i) s += w[i] * p0[i];
    #pragma unroll 4
    for (int i = 0; i < 128; ++i) s += w[i + 128] * p1[i];
    bias[o] = s;
}

// ---- pass 1: zero the prepended zero-block outputs (silu chain of 0 -> 0) ----
__global__ void zero_kernel(float* __restrict__ out) {
    int i = blockIdx.x * 256 + threadIdx.x;  // 4096 = 32 heads * 128
    int bh = i >> 7, d = i & 127;
    out[(size_t)bh * NBLK * DQ + d] = 0.f;
}

// ---- pass 2: fused compressor ----
// grid: 32 heads * 64 groups = 2048 blocks, 512 threads (8 waves).
// Wave (mg,ng): ng owns n-tiles {2ng, 2ng+1}; mg splits the m-tiles.
// A-fragment LDS reads amortize over 2 n-tiles (4x input reads vs 8x).
// k-rows loaded ONCE (windows overlap 50%): 144 rows, 1 barrier, 6 total.
__global__ __launch_bounds__(512, 4)
void fused_kernel(const float* __restrict__ kin,
                  const short* __restrict__ wdb,
                  const float* __restrict__ bias0,
                  float* __restrict__ out) {
    __shared__ __align__(16) unsigned char lds[69632];
    const short* wsb = wdb + 163840;

    const int bh = blockIdx.x >> 6;           // 0..31
    const int w0 = (blockIdx.x & 63) * WPB;   // first window of this group
    const int tid  = threadIdx.x;
    const int lane = tid & 63;
    const int wave = tid >> 6;
    const int ng   = wave & 3;                // n-group: owns n-tiles 2ng,2ng+1
    const int mg   = wave >> 2;               // m-group 0..1
    const int kl   = lane >> 4;               // 0..3
    const int nl   = lane & 15;               // 0..15
    const int nt0  = ng * 2, nt1 = ng * 2 + 1;

    const float* kb = kin + (size_t)bh * SQ * DQ;

    // ---- phase A: load 144 distinct rows (8 windows, 50% overlap) once ----
    #pragma unroll
    for (int it = 0; it < 5; ++it) {
        int task = tid + it * 512;            // 2304 tasks = 144 rows x 16 chunks
        if (task < 2304) {
            int rr = task >> 4;               // 0..143
            int c8 = task & 15;
            int srow = STR * w0 + rr;
            if (srow > SQ - 1) srow = SQ - 1; // clamp (garbage window 511 only)
            const float* kp = kb + (size_t)srow * DQ + c8 * 8;
            f32x4 a0 = *(const f32x4*)kp;
            f32x4 a1 = *(const f32x4*)(kp + 4);
            s16x8 v;
            v[0] = f2bf(a0[0]); v[1] = f2bf(a0[1]); v[2] = f2bf(a0[2]); v[3] = f2bf(a0[3]);
            v[4] = f2bf(a1[0]); v[5] = f2bf(a1[1]); v[6] = f2bf(a1[2]); v[7] = f2bf(a1[3]);
            *(s16x8*)(lds + swz(R_KIN + (unsigned)((rr << 8) + (c8 << 4)))) = v;
        }
    }

    // stage-0 bias fragments (acc init; pe folded into bias0)
    f32x4 bias_a, bias_b;
    #pragma unroll
    for (int r4 = 0; r4 < 4; ++r4) {
        bias_a[r4] = bias0[(kl * 4 + r4) * 128 + nt0 * 16 + nl];
        bias_b[r4] = bias0[(kl * 4 + r4) * 128 + nt1 * 16 + nl];
    }
    // stage-0 B fragments for both owned n-tiles
    s16x8 b0a[8], b0b[8];
    #pragma unroll
    for (int kt = 0; kt < 8; ++kt) {
        b0a[kt] = *(const s16x8*)(wdb + (nt0 * 16 + nl) * 256 + kt * 32 + kl * 8);
        b0b[kt] = *(const s16x8*)(wdb + (nt1 * 16 + nl) * 256 + kt * 32 + kl * 8);
    }
    __syncthreads();

    // ---- stage 0: 8 m-tiles (= windows); mg takes 4 ----
    for (int mm = mg * 4; mm < mg * 4 + 4; ++mm) {
        // A-row nl of window mm = kin rows 16mm+2nl, +1 (contiguous 512B)
        f32x4 acc0 = bias_a, acc1 = bias_b;
        #pragma unroll
        for (int kt = 0; kt < 8; ++kt) {
            unsigned bb = R_KIN + (unsigned)((mm << 12) + (nl << 9) + (kt << 6) + (kl << 4));
            s16x8 a = *(const s16x8*)(lds + swz(bb));
            acc0 = __builtin_amdgcn_mfma_f32_16x16x32_bf16(a, b0a[kt], acc0, 0, 0, 0);
            acc1 = __builtin_amdgcn_mfma_f32_16x16x32_bf16(a, b0b[kt], acc1, 0, 0, 0);
        }
        #pragma unroll
        for (int r4 = 0; r4 < 4; ++r4) {
            int orow = mm * 16 + kl * 4 + r4;           // 0..127
            unsigned ob = R_S0 + (unsigned)((orow << 8) + ((nt0 * 16 + nl) << 1));
            *(short*)(lds + swz(ob)) = f2bf(silu(acc0[r4]));
            ob = R_S0 + (unsigned)((orow << 8) + ((nt1 * 16 + nl) << 1));
            *(short*)(lds + swz(ob)) = f2bf(silu(acc1[r4]));
        }
    }
    __syncthreads();

    // ---- stages 1..4: A-row t reads rows 2t,2t+1 of the packed input ----
    const unsigned rin[4]  = {R_S0, R_S1, R_S2, R_S3};
    const unsigned rout[4] = {R_S1, R_S2, R_S3, R_S4};
    #pragma unroll
    for (int s = 1; s <= 4; ++s) {
        const short* W = wdb + s * 32768;
        s16x8 bfa[8], bfb[8];
        #pragma unroll
        for (int kt = 0; kt < 8; ++kt) {
            bfa[kt] = *(const s16x8*)(W + (nt0 * 16 + nl) * 256 + kt * 32 + kl * 8);
            bfb[kt] = *(const s16x8*)(W + (nt1 * 16 + nl) * 256 + kt * 32 + kl * 8);
        }
        const unsigned inoff  = rin[s - 1];
        const unsigned outoff = rout[s - 1];
        const int Arows = 64 >> (s - 1);     // valid A-rows = out rows: 64,32,16,8
        const int mt = (Arows + 15) >> 4;    // 4,2,1,1
        int mbeg, mend;
        if (mt >= 2) { int half = mt >> 1; mbeg = mg * half; mend = mbeg + half; }
        else         { mbeg = 0; mend = (mg == 0) ? 1 : 0; }

        for (int m = mbeg; m < mend; ++m) {
            int t = m * 16 + nl;
            if (t > Arows - 1) t = Arows - 1;          // clamp dead rows (stage 4)
            f32x4 acc0 = {0.f, 0.f, 0.f, 0.f};
            f32x4 acc1 = {0.f, 0.f, 0.f, 0.f};
            #pragma unroll
            for (int kt = 0; kt < 8; ++kt) {
                unsigned bb = inoff + (unsigned)((t << 9) + (kt << 6) + (kl << 4));
                s16x8 a = *(const s16x8*)(lds + swz(bb));
                acc0 = __builtin_amdgcn_mfma_f32_16x16x32_bf16(a, bfa[kt], acc0, 0, 0, 0);
                acc1 = __builtin_amdgcn_mfma_f32_16x16x32_bf16(a, bfb[kt], acc1, 0, 0, 0);
            }
            #pragma unroll
            for (int r4 = 0; r4 < 4; ++r4) {
                int orow = m * 16 + kl * 4 + r4;
                if (orow < Arows) {
                    unsigned ob = outoff + (unsigned)((orow << 8) + ((nt0 * 16 + nl) << 1));
                    *(short*)(lds + swz(ob)) = f2bf(silu(acc0[r4]));
                    ob = outoff + (unsigned)((orow << 8) + ((nt1 * 16 + nl) << 1));
                    *(short*)(lds + swz(ob)) = f2bf(silu(acc1[r4]));
                }
            }
        }
        __syncthreads();
    }

    // ---- w_stop (no activation): 8 rows x 128, K=128 -> global f32 ----
    if (mg == 0) {
        s16x8 bfa[4], bfb[4];
        #pragma unroll
        for (int kt = 0; kt < 4; ++kt) {
            bfa[kt] = *(const s16x8*)(wsb + (nt0 * 16 + nl) * 128 + kt * 32 + kl * 8);
            bfb[kt] = *(const s16x8*)(wsb + (nt1 * 16 + nl) * 128 + kt * 32 + kl * 8);
        }
        int t = (nl < 8) ? nl : 7;
        f32x4 acc0 = {0.f, 0.f, 0.f, 0.f};
        f32x4 acc1 = {0.f, 0.f, 0.f, 0.f};
        #pragma unroll
        for (int kt = 0; kt < 4; ++kt) {
            unsigned bb = R_S4 + (unsigned)((t << 8) + (kt << 6) + (kl << 4));
            s16x8 a = *(const s16x8*)(lds + swz(bb));
            acc0 = __builtin_amdgcn_mfma_f32_16x16x32_bf16(a, bfa[kt], acc0, 0, 0, 0);
            acc1 = __builtin_amdgcn_mfma_f32_16x16x32_bf16(a, bfb[kt], acc1, 0, 0, 0);
        }
        if (kl < 2) {
            #pragma unroll
            for (int r4 = 0; r4 < 4; ++r4) {
                int w = w0 + kl * 4 + r4;     // C row = window index (0..7)
                if (w < NWIN) {
                    size_t o = ((size_t)bh * NBLK + (w + 1)) * DQ + nl;
                    out[o + nt0 * 16] = acc0[r4];
                    out[o + nt1 * 16] = acc1[r4];
                }
            }
        }
    }
}

extern "C" void kernel_launch(void* const* d_in, const int* in_sizes, int n_in,
                              void* d_out, int out_size, void* d_ws, size_t ws_size,
                              hipStream_t stream) {
    const float* kin   = (const float*)d_in[0];
    const float* pe    = (const float*)d_in[1];
    const float* wdown = (const float*)d_in[2];
    const float* wstop = (const float*)d_in[3];
    float* out = (float*)d_out;
    short* wbf  = (short*)d_ws;                       // 180224 shorts
    float* bias = (float*)((char*)d_ws + 360448);     // f32[2048]

    convw_kernel<<<704, 256, 0, stream>>>(wdown, wstop, wbf);
    bias0_kernel<<<8, 256, 0, stream>>>(wdown, pe, bias);
    zero_kernel<<<16, 256, 0, stream>>>(out);
    fused_kernel<<<BQ * HQ * NWG_PER_HEAD, 512, 0, stream>>>(kin, wbf, bias, out);
}

// Round 6
// 127.363 us; speedup vs baseline: 1.3216x; 1.3216x over previous
//
#include <hip/hip_runtime.h>

// Problem constants (from reference)
#define BQ 2
#define HQ 16
#define SQ 8192
#define DQ 128
#define STR 16
#define NWIN 511     // (8192-32)/16 + 1
#define NBLK 512     // NWIN + 1 zero block
#define WPB 4        // windows per workgroup
#define NWG_PER_HEAD 128  // ceil(511/4)

typedef float f32x4 __attribute__((ext_vector_type(4)));
typedef short s16x8 __attribute__((ext_vector_type(8)));
typedef short s16x4 __attribute__((ext_vector_type(4)));

// LDS 36 KB map (pyramid reuses the dead kin region):
//   kin @0     [80 rows][256B] = 20480   (4 windows, 50% overlap, loaded once)
//   s0  @20480 [64][256] = 16384
//   s1  @0     [32][256] =  8192  (kin dead)
//   s2  @8192  [16][256] =  4096
//   s3  @12288 [8][256]  =  2048
//   s4  @14336 [4][256]  =  1024
#define R_KIN 0u
#define R_S0  20480u
#define R_S1  0u
#define R_S2  8192u
#define R_S3  12288u
#define R_S4  14336u

// XOR swizzle keyed on 512B granule (G4/T2): spreads stride-256/512B row
// accesses across bank groups. Involution on global LDS byte offsets.
static __device__ __forceinline__ unsigned swz(unsigned b) {
    return b ^ (((b >> 9) & 7u) << 4);
}

static __device__ __forceinline__ short f2bf(float f) {
    __bf16 h = (__bf16)f;
    return __builtin_bit_cast(short, h);
}

static __device__ __forceinline__ float silu(float v) {
    return v / (1.f + __expf(-v));
}

// ---- pass 0a: weights f32 -> bf16, PRE-PERMUTED into fragment order ----
// down:  o[s*32768 + ct*4096 + kt*512 + lane*8 + e] = W_s[ct*16+(lane&15)][kt*32+(lane>>4)*8+e]
// stop:  o[163840 + ct*2048 + kt*512 + lane*8 + e] = Wstop[ct*16+(lane&15)][kt*32+(lane>>4)*8+e]
// -> each wave's 8 fragment loads are 1KB-contiguous (perfect coalescing).
__global__ void convw_kernel(const float* __restrict__ wd,
                             const float* __restrict__ wstop,
                             short* __restrict__ o) {
    int i = blockIdx.x * 256 + threadIdx.x;
    if (i < 163840) {
        int s   = i >> 15;
        int r   = i & 32767;
        int ct  = r >> 12;
        int r2  = r & 4095;
        int kt  = r2 >> 9;
        int r3  = r2 & 511;
        int ln  = r3 >> 3;
        int e   = r3 & 7;
        int ch  = ct * 16 + (ln & 15);
        int k   = kt * 32 + (ln >> 4) * 8 + e;
        o[i] = f2bf(wd[((size_t)(s * 128 + ch)) * 256 + k]);
    } else if (i < 180224) {
        int j   = i - 163840;
        int ct  = j >> 11;
        int r2  = j & 2047;
        int kt  = r2 >> 9;
        int r3  = r2 & 511;
        int ln  = r3 >> 3;
        int e   = r3 & 7;
        int ch  = ct * 16 + (ln & 15);
        int k   = kt * 32 + (ln >> 4) * 8 + e;
        o[i] = f2bf(wstop[ch * 128 + k]);
    }
}

// ---- pass 0b: bias0[j][c] = sum_i W0[c][i] * concat(pe[2j],pe[2j+1])[i] ----
__global__ void bias0_kernel(const float* __restrict__ wd,
                             const float* __restrict__ pe,
                             float* __restrict__ bias) {
    int o = blockIdx.x * 256 + threadIdx.x;   // 0..2047
    int j = o >> 7;
    int c = o & 127;
    const float* w  = wd + (size_t)c * 256;
    const float* p0 = pe + (2 * j) * DQ;
    const float* p1 = pe + (2 * j + 1) * DQ;
    float s = 0.f;
    #pragma unroll 4
    for (int i = 0; i < 128; ++i) s += w[i] * p0[i];
    #pragma unroll 4
    for (int i = 0; i < 128; ++i) s += w[i + 128] * p1[i];
    bias[o] = s;
}

// ---- pass 1: zero the prepended zero-block outputs (silu chain of 0 -> 0) ----
__global__ void zero_kernel(float* __restrict__ out) {
    int i = blockIdx.x * 256 + threadIdx.x;  // 4096 = 32 heads * 128
    int bh = i >> 7, d = i & 127;
    out[(size_t)bh * NBLK * DQ + d] = 0.f;
}

// ---- pass 2: fused compressor, SWAPPED-OPERAND form (computes out^T tiles) ----
// grid: 32 heads * 128 groups = 4096 blocks, 512 threads (8 waves).
// Wave = channel-tile ct (16 out-channels); loops over data-row n-tiles.
// A-operand = W fragments (regs, 32 VGPR); B-operand = activations from LDS
// (b128, swizzled, 2-way max). D: lane holds 4 consecutive channels of one
// data-row -> epilogue is ONE ds_write_b64; stop stage is ONE dwordx4 store.
// 36KB LDS + VGPR<=64 -> 4 blocks/CU = 32 waves/CU.
__global__ __launch_bounds__(512, 8)
void fused_kernel(const float* __restrict__ kin,
                  const short* __restrict__ wdb,
                  const float* __restrict__ bias0,
                  float* __restrict__ out) {
    __shared__ __align__(16) unsigned char lds[36864];

    const int bh = blockIdx.x >> 7;            // 0..31
    const int w0 = (blockIdx.x & 127) * WPB;   // first window of this group
    const int tid  = threadIdx.x;
    const int lane = tid & 63;
    const int ct   = tid >> 6;                 // wave = channel-tile 0..7
    const int kl   = lane >> 4;                // 0..3
    const int nl   = lane & 15;                // 0..15

    const float* kb = kin + (size_t)bh * SQ * DQ;

    // ---- phase A: 80 rows x 16 chunks = 1280 tasks, loaded once ----
    #pragma unroll
    for (int it = 0; it < 3; ++it) {
        int task = tid + it * 512;
        if (task < 1280) {
            int rr = task >> 4;               // 0..79
            int c8 = task & 15;
            int srow = STR * w0 + rr;
            if (srow > SQ - 1) srow = SQ - 1; // clamp (feeds invalid window only)
            const float* kp = kb + (size_t)srow * DQ + c8 * 8;
            f32x4 a0 = *(const f32x4*)kp;
            f32x4 a1 = *(const f32x4*)(kp + 4);
            s16x8 v;
            v[0] = f2bf(a0[0]); v[1] = f2bf(a0[1]); v[2] = f2bf(a0[2]); v[3] = f2bf(a0[3]);
            v[4] = f2bf(a1[0]); v[5] = f2bf(a1[1]); v[6] = f2bf(a1[2]); v[7] = f2bf(a1[3]);
            *(s16x8*)(lds + swz(R_KIN + (unsigned)((rr << 8) + (c8 << 4)))) = v;
        }
    }

    // W0 fragments (A-operand) + stage-0 bias (pe folded; lane's 4 channels)
    s16x8 wf[8];
    #pragma unroll
    for (int kt = 0; kt < 8; ++kt)
        wf[kt] = *(const s16x8*)(wdb + ct * 4096 + kt * 512 + lane * 8);
    const f32x4 bias = *(const f32x4*)(bias0 + nl * 128 + ct * 16 + kl * 4);

    __syncthreads();   // kin ready

    // ---- stage 0: 4 n-tiles (data-rows 16n..16n+15); K=256 ----
    // B-frag row for data-row d=16n+nl: kin row 16n+2*nl (+1 for k>=128)
    #pragma unroll
    for (int n = 0; n < 4; ++n) {
        f32x4 acc = bias;
        #pragma unroll
        for (int kt = 0; kt < 8; ++kt) {
            unsigned row = (unsigned)(16 * n + 2 * nl + (kt >> 2));
            unsigned bb = R_KIN + (row << 8) + (unsigned)(((kt & 3) << 6) + (kl << 4));
            s16x8 a = *(const s16x8*)(lds + swz(bb));
            acc = __builtin_amdgcn_mfma_f32_16x16x32_bf16(wf[kt], a, acc, 0, 0, 0);
        }
        s16x4 v;
        v[0] = f2bf(silu(acc[0])); v[1] = f2bf(silu(acc[1]));
        v[2] = f2bf(silu(acc[2])); v[3] = f2bf(silu(acc[3]));
        unsigned d = (unsigned)(n * 16 + nl);
        *(s16x4*)(lds + swz(R_S0 + (d << 8) + (unsigned)(ct * 32 + kl * 8))) = v;
    }

    // ---- stages 1..4: in rows 64,32,16,8 -> out rows 32,16,8,4 ----
    const unsigned rin[4]  = {R_S0, R_S1, R_S2, R_S3};
    const unsigned rout[4] = {R_S1, R_S2, R_S3, R_S4};
    #pragma unroll
    for (int s = 1; s <= 4; ++s) {
        // next-stage W frags issued before the barrier (latency overlaps sync)
        #pragma unroll
        for (int kt = 0; kt < 8; ++kt)
            wf[kt] = *(const s16x8*)(wdb + s * 32768 + ct * 4096 + kt * 512 + lane * 8);
        __syncthreads();   // previous stage's output ready

        const int outRows = 32 >> (s - 1);       // 32,16,8,4
        const int nt = (outRows + 15) >> 4;      // 2,1,1,1
        for (int n = 0; n < nt; ++n) {
            int d = n * 16 + nl;
            int dc = (d < outRows) ? d : outRows - 1;   // clamp dead lanes
            f32x4 acc = {0.f, 0.f, 0.f, 0.f};
            #pragma unroll
            for (int kt = 0; kt < 8; ++kt) {
                unsigned row = (unsigned)(2 * dc + (kt >> 2));
                unsigned bb = rin[s - 1] + (row << 8) + (unsigned)(((kt & 3) << 6) + (kl << 4));
                s16x8 a = *(const s16x8*)(lds + swz(bb));
                acc = __builtin_amdgcn_mfma_f32_16x16x32_bf16(wf[kt], a, acc, 0, 0, 0);
            }
            if (d < outRows) {
                s16x4 v;
                v[0] = f2bf(silu(acc[0])); v[1] = f2bf(silu(acc[1]));
                v[2] = f2bf(silu(acc[2])); v[3] = f2bf(silu(acc[3]));
                *(s16x4*)(lds + swz(rout[s - 1] + ((unsigned)d << 8) + (unsigned)(ct * 32 + kl * 8))) = v;
            }
        }
    }

    // ---- w_stop: input R_S4 [4][256B], K=128, no activation -> global f32 ----
    #pragma unroll
    for (int kt = 0; kt < 4; ++kt)
        wf[kt] = *(const s16x8*)(wdb + 163840 + ct * 2048 + kt * 512 + lane * 8);
    __syncthreads();   // s4 ready
    {
        int d = nl;
        int dc = (d < WPB) ? d : WPB - 1;
        f32x4 acc = {0.f, 0.f, 0.f, 0.f};
        #pragma unroll
        for (int kt = 0; kt < 4; ++kt) {
            unsigned bb = R_S4 + ((unsigned)dc << 8) + (unsigned)((kt << 6) + (kl << 4));
            s16x8 a = *(const s16x8*)(lds + swz(bb));
            acc = __builtin_amdgcn_mfma_f32_16x16x32_bf16(wf[kt], a, acc, 0, 0, 0);
        }
        int w = w0 + d;
        if (d < WPB && w < NWIN) {
            // lane holds channels ct*16+kl*4 .. +3 of window w: one dwordx4
            *(f32x4*)(out + ((size_t)bh * NBLK + (w + 1)) * DQ + ct * 16 + kl * 4) = acc;
        }
    }
}

extern "C" void kernel_launch(void* const* d_in, const int* in_sizes, int n_in,
                              void* d_out, int out_size, void* d_ws, size_t ws_size,
                              hipStream_t stream) {
    const float* kin   = (const float*)d_in[0];
    const float* pe    = (const float*)d_in[1];
    const float* wdown = (const float*)d_in[2];
    const float* wstop = (const float*)d_in[3];
    float* out = (float*)d_out;
    short* wbf  = (short*)d_ws;                       // 180224 shorts (frag-order)
    float* bias = (float*)((char*)d_ws + 360448);     // f32[2048]

    convw_kernel<<<704, 256, 0, stream>>>(wdown, wstop, wbf);
    bias0_kernel<<<8, 256, 0, stream>>>(wdown, pe, bias);
    zero_kernel<<<16, 256, 0, stream>>>(out);
    fused_kernel<<<BQ * HQ * NWG_PER_HEAD, 512, 0, stream>>>(kin, wbf, bias, out);
}

// Round 7
// 109.514 us; speedup vs baseline: 1.5370x; 1.1630x over previous
//
#include <hip/hip_runtime.h>

// Problem constants (from reference)
#define BQ 2
#define HQ 16
#define SQ 8192
#define DQ 128
#define STR 16
#define NWIN 511     // (8192-32)/16 + 1
#define NBLK 512     // NWIN + 1 zero block
#define WPB 4        // windows per workgroup
#define NWG_PER_HEAD 128  // ceil(511/4)

typedef float f32x4 __attribute__((ext_vector_type(4)));
typedef short s16x8 __attribute__((ext_vector_type(8)));
typedef short s16x4 __attribute__((ext_vector_type(4)));

// LDS 36 KB map (pyramid reuses the dead kin region):
//   kin @0     [80 rows][256B] = 20480   (4 windows, 50% overlap, loaded once)
//   s0  @20480 [64][256] = 16384
//   s1  @0     [32][256] =  8192  (kin dead)
//   s2  @8192  [16][256] =  4096
//   s3  @12288 [8][256]  =  2048
//   s4  @14336 [4][256]  =  1024
#define R_KIN 0u
#define R_S0  20480u
#define R_S1  0u
#define R_S2  8192u
#define R_S3  12288u
#define R_S4  14336u

// XOR swizzle keyed on 512B granule (G4/T2). Involution on global LDS byte
// offsets; writers and readers apply it to the same global byte.
static __device__ __forceinline__ unsigned swz(unsigned b) {
    return b ^ (((b >> 9) & 7u) << 4);
}

static __device__ __forceinline__ short f2bf(float f) {
    __bf16 h = (__bf16)f;
    return __builtin_bit_cast(short, h);
}

static __device__ __forceinline__ float silu(float v) {
    return v / (1.f + __expf(-v));
}

// ---- pass 0a: weights f32 -> bf16, PRE-PERMUTED into fragment order ----
// down:  o[s*32768 + ct*4096 + kt*512 + lane*8 + e] = W_s[ct*16+(lane&15)][kt*32+(lane>>4)*8+e]
// stop:  o[163840 + ct*2048 + kt*512 + lane*8 + e] = Wstop[ct*16+(lane&15)][kt*32+(lane>>4)*8+e]
__global__ void convw_kernel(const float* __restrict__ wd,
                             const float* __restrict__ wstop,
                             short* __restrict__ o) {
    int i = blockIdx.x * 256 + threadIdx.x;
    if (i < 163840) {
        int s   = i >> 15;
        int r   = i & 32767;
        int ct  = r >> 12;
        int r2  = r & 4095;
        int kt  = r2 >> 9;
        int r3  = r2 & 511;
        int ln  = r3 >> 3;
        int e   = r3 & 7;
        int ch  = ct * 16 + (ln & 15);
        int k   = kt * 32 + (ln >> 4) * 8 + e;
        o[i] = f2bf(wd[((size_t)(s * 128 + ch)) * 256 + k]);
    } else if (i < 180224) {
        int j   = i - 163840;
        int ct  = j >> 11;
        int r2  = j & 2047;
        int kt  = r2 >> 9;
        int r3  = r2 & 511;
        int ln  = r3 >> 3;
        int e   = r3 & 7;
        int ch  = ct * 16 + (ln & 15);
        int k   = kt * 32 + (ln >> 4) * 8 + e;
        o[i] = f2bf(wstop[ch * 128 + k]);
    }
}

// ---- pass 0b: bias0[j][c] = sum_i W0[c][i] * concat(pe[2j],pe[2j+1])[i] ----
__global__ void bias0_kernel(const float* __restrict__ wd,
                             const float* __restrict__ pe,
                             float* __restrict__ bias) {
    int o = blockIdx.x * 256 + threadIdx.x;   // 0..2047
    int j = o >> 7;
    int c = o & 127;
    const float* w  = wd + (size_t)c * 256;
    const float* p0 = pe + (2 * j) * DQ;
    const float* p1 = pe + (2 * j + 1) * DQ;
    float s = 0.f;
    #pragma unroll 4
    for (int i = 0; i < 128; ++i) s += w[i] * p0[i];
    #pragma unroll 4
    for (int i = 0; i < 128; ++i) s += w[i + 128] * p1[i];
    bias[o] = s;
}

// ---- pass 1: zero the prepended zero-block outputs (silu chain of 0 -> 0) ----
__global__ void zero_kernel(float* __restrict__ out) {
    int i = blockIdx.x * 256 + threadIdx.x;  // 4096 = 32 heads * 128
    int bh = i >> 7, d = i & 127;
    out[(size_t)bh * NBLK * DQ + d] = 0.f;
}

// ---- pass 2: fused compressor, swapped-operand form, K-HALVED wf ----
// Wave = channel-tile ct. A-operand = W frags (16 regs per half), B-operand =
// activations (LDS b128). K-loop split in halves so peak VGPR ~50 < 64 cap:
// no spills at (512,8) -> 4 blocks/CU = 32 waves/CU.
__global__ __launch_bounds__(512, 8)
void fused_kernel(const float* __restrict__ kin,
                  const short* __restrict__ wdb,
                  const float* __restrict__ bias0,
                  float* __restrict__ out) {
    __shared__ __align__(16) unsigned char lds[36864];

    const int bh = blockIdx.x >> 7;            // 0..31
    const int w0 = (blockIdx.x & 127) * WPB;   // first window of this group
    const int tid  = threadIdx.x;
    const int lane = tid & 63;
    const int ct   = tid >> 6;                 // wave = channel-tile 0..7
    const int kl   = lane >> 4;                // 0..3
    const int nl   = lane & 15;                // 0..15

    const float* kb = kin + (size_t)bh * SQ * DQ;

    // ---- phase A: 80 rows x 16 chunks = 1280 tasks, loaded once ----
    #pragma unroll
    for (int it = 0; it < 3; ++it) {
        int task = tid + it * 512;
        if (task < 1280) {
            int rr = task >> 4;               // 0..79
            int c8 = task & 15;
            int srow = STR * w0 + rr;
            if (srow > SQ - 1) srow = SQ - 1; // clamp (feeds invalid window only)
            const float* kp = kb + (size_t)srow * DQ + c8 * 8;
            f32x4 a0 = *(const f32x4*)kp;
            f32x4 a1 = *(const f32x4*)(kp + 4);
            s16x8 v;
            v[0] = f2bf(a0[0]); v[1] = f2bf(a0[1]); v[2] = f2bf(a0[2]); v[3] = f2bf(a0[3]);
            v[4] = f2bf(a1[0]); v[5] = f2bf(a1[1]); v[6] = f2bf(a1[2]); v[7] = f2bf(a1[3]);
            *(s16x8*)(lds + swz(R_KIN + (unsigned)((rr << 8) + (c8 << 4)))) = v;
        }
    }

    const f32x4 bias = *(const f32x4*)(bias0 + nl * 128 + ct * 16 + kl * 4);
    __syncthreads();   // kin ready

    // one K-half of one output tile: 4 b128 reads + 4 MFMAs into accv
#define K_HALF(base_row, colbase, accv) {                                      \
        unsigned rb = (colbase) + ((unsigned)(base_row) << 8) + (unsigned)(kl << 4); \
        s16x8 aa0 = *(const s16x8*)(lds + swz(rb));                            \
        s16x8 aa1 = *(const s16x8*)(lds + swz(rb + 64u));                      \
        s16x8 aa2 = *(const s16x8*)(lds + swz(rb + 128u));                     \
        s16x8 aa3 = *(const s16x8*)(lds + swz(rb + 192u));                     \
        accv = __builtin_amdgcn_mfma_f32_16x16x32_bf16(wfh[0], aa0, accv, 0, 0, 0); \
        accv = __builtin_amdgcn_mfma_f32_16x16x32_bf16(wfh[1], aa1, accv, 0, 0, 0); \
        accv = __builtin_amdgcn_mfma_f32_16x16x32_bf16(wfh[2], aa2, accv, 0, 0, 0); \
        accv = __builtin_amdgcn_mfma_f32_16x16x32_bf16(wfh[3], aa3, accv, 0, 0, 0); }

    // ---- stage 0: 4 n-tiles; K=256 split in two halves of 128 ----
    {
        f32x4 acc0 = bias, acc1 = bias, acc2 = bias, acc3 = bias;
        #pragma unroll
        for (int half = 0; half < 2; ++half) {
            s16x8 wfh[4];
            #pragma unroll
            for (int kt = 0; kt < 4; ++kt)
                wfh[kt] = *(const s16x8*)(wdb + ct * 4096 + (half * 4 + kt) * 512 + lane * 8);
            // B row for data-row d=16n+nl is kin row 16n+2nl (+half)
            K_HALF(2 * nl + half,      R_KIN, acc0);
            K_HALF(16 + 2 * nl + half, R_KIN, acc1);
            K_HALF(32 + 2 * nl + half, R_KIN, acc2);
            K_HALF(48 + 2 * nl + half, R_KIN, acc3);
        }
        #pragma unroll
        for (int n = 0; n < 4; ++n) {
            f32x4 acc = (n == 0) ? acc0 : (n == 1) ? acc1 : (n == 2) ? acc2 : acc3;
            s16x4 v;
            v[0] = f2bf(silu(acc[0])); v[1] = f2bf(silu(acc[1]));
            v[2] = f2bf(silu(acc[2])); v[3] = f2bf(silu(acc[3]));
            unsigned d = (unsigned)(n * 16 + nl);
            *(s16x4*)(lds + swz(R_S0 + (d << 8) + (unsigned)(ct * 32 + kl * 8))) = v;
        }
    }
    __syncthreads();

    // ---- stage 1: 64 in rows -> 32 out rows (2 n-tiles) ----
    {
        f32x4 acc0 = {0.f, 0.f, 0.f, 0.f};
        f32x4 acc1 = {0.f, 0.f, 0.f, 0.f};
        #pragma unroll
        for (int half = 0; half < 2; ++half) {
            s16x8 wfh[4];
            #pragma unroll
            for (int kt = 0; kt < 4; ++kt)
                wfh[kt] = *(const s16x8*)(wdb + 32768 + ct * 4096 + (half * 4 + kt) * 512 + lane * 8);
            K_HALF(2 * nl + half,      R_S0, acc0);
            K_HALF(32 + 2 * nl + half, R_S0, acc1);
        }
        #pragma unroll
        for (int n = 0; n < 2; ++n) {
            f32x4 acc = n ? acc1 : acc0;
            s16x4 v;
            v[0] = f2bf(silu(acc[0])); v[1] = f2bf(silu(acc[1]));
            v[2] = f2bf(silu(acc[2])); v[3] = f2bf(silu(acc[3]));
            unsigned d = (unsigned)(n * 16 + nl);
            *(s16x4*)(lds + swz(R_S1 + (d << 8) + (unsigned)(ct * 32 + kl * 8))) = v;
        }
    }
    __syncthreads();

    // ---- stages 2..4: 1 n-tile each, shrinking valid rows (16,8,4) ----
    const unsigned rin[3]  = {R_S1, R_S2, R_S3};
    const unsigned rout[3] = {R_S2, R_S3, R_S4};
    #pragma unroll
    for (int s = 2; s <= 4; ++s) {
        const int outRows = 32 >> (s - 1);       // 16,8,4
        int d = nl;
        int dc = (d < outRows) ? d : outRows - 1;
        f32x4 acc0 = {0.f, 0.f, 0.f, 0.f};
        #pragma unroll
        for (int half = 0; half < 2; ++half) {
            s16x8 wfh[4];
            #pragma unroll
            for (int kt = 0; kt < 4; ++kt)
                wfh[kt] = *(const s16x8*)(wdb + s * 32768 + ct * 4096 + (half * 4 + kt) * 512 + lane * 8);
            K_HALF(2 * dc + half, rin[s - 2], acc0);
        }
        if (d < outRows) {
            s16x4 v;
            v[0] = f2bf(silu(acc0[0])); v[1] = f2bf(silu(acc0[1]));
            v[2] = f2bf(silu(acc0[2])); v[3] = f2bf(silu(acc0[3]));
            *(s16x4*)(lds + swz(rout[s - 2] + ((unsigned)d << 8) + (unsigned)(ct * 32 + kl * 8))) = v;
        }
        __syncthreads();
    }

    // ---- w_stop: input R_S4 [4][256B], K=128, no activation -> global f32 ----
    {
        s16x8 wfh[4];
        #pragma unroll
        for (int kt = 0; kt < 4; ++kt)
            wfh[kt] = *(const s16x8*)(wdb + 163840 + ct * 2048 + kt * 512 + lane * 8);
        int d = nl;
        int dc = (d < WPB) ? d : WPB - 1;
        f32x4 acc = {0.f, 0.f, 0.f, 0.f};
        {
            unsigned rb = R_S4 + ((unsigned)dc << 8) + (unsigned)(kl << 4);
            s16x8 aa0 = *(const s16x8*)(lds + swz(rb));
            s16x8 aa1 = *(const s16x8*)(lds + swz(rb + 64u));
            s16x8 aa2 = *(const s16x8*)(lds + swz(rb + 128u));
            s16x8 aa3 = *(const s16x8*)(lds + swz(rb + 192u));
            acc = __builtin_amdgcn_mfma_f32_16x16x32_bf16(wfh[0], aa0, acc, 0, 0, 0);
            acc = __builtin_amdgcn_mfma_f32_16x16x32_bf16(wfh[1], aa1, acc, 0, 0, 0);
            acc = __builtin_amdgcn_mfma_f32_16x16x32_bf16(wfh[2], aa2, acc, 0, 0, 0);
            acc = __builtin_amdgcn_mfma_f32_16x16x32_bf16(wfh[3], aa3, acc, 0, 0, 0);
        }
        int w = w0 + d;
        if (d < WPB && w < NWIN) {
            // lane holds channels ct*16+kl*4 .. +3 of window w: one dwordx4
            *(f32x4*)(out + ((size_t)bh * NBLK + (w + 1)) * DQ + ct * 16 + kl * 4) = acc;
        }
    }
#undef K_HALF
}

extern "C" void kernel_launch(void* const* d_in, const int* in_sizes, int n_in,
                              void* d_out, int out_size, void* d_ws, size_t ws_size,
                              hipStream_t stream) {
    const float* kin   = (const float*)d_in[0];
    const float* pe    = (const float*)d_in[1];
    const float* wdown = (const float*)d_in[2];
    const float* wstop = (const float*)d_in[3];
    float* out = (float*)d_out;
    short* wbf  = (short*)d_ws;                       // 180224 shorts (frag-order)
    float* bias = (float*)((char*)d_ws + 360448);     // f32[2048]

    convw_kernel<<<704, 256, 0, stream>>>(wdown, wstop, wbf);
    bias0_kernel<<<8, 256, 0, stream>>>(wdown, pe, bias);
    zero_kernel<<<16, 256, 0, stream>>>(out);
    fused_kernel<<<BQ * HQ * NWG_PER_HEAD, 512, 0, stream>>>(kin, wbf, bias, out);
}

// Round 9
// 91.957 us; speedup vs baseline: 1.8305x; 1.1909x over previous
//
#include <hip/hip_runtime.h>

// Problem constants (from reference)
#define BQ 2
#define HQ 16
#define SQ 8192
#define DQ 128
#define STR 16
#define NWIN 511     // (8192-32)/16 + 1
#define NBLK 512     // NWIN + 1 zero block
#define WPB 4        // windows per workgroup
#define NWG_PER_HEAD 128  // ceil(511/4)

typedef float f32x4 __attribute__((ext_vector_type(4)));
typedef short s16x8 __attribute__((ext_vector_type(8)));
typedef short s16x4 __attribute__((ext_vector_type(4)));

// LDS 36 KB map (pyramid reuses the dead kin region):
//   kin @0     [80 rows][256B] = 20480   (4 windows, 50% overlap, loaded once)
//   s0  @20480 [64][256] = 16384
//   s1  @0     [32][256] =  8192  (kin dead)
//   s2  @8192  [16][256] =  4096
//   s3  @12288 [8][256]  =  2048
//   s4  @14336 [4][256]  =  1024
#define R_KIN 0u
#define R_S0  20480u
#define R_S1  0u
#define R_S2  8192u
#define R_S3  12288u
#define R_S4  14336u

// XOR swizzle keyed on 512B granule (G4/T2). Involution on global LDS byte
// offsets. HOIST SOUNDNESS (R8 bug fix): pre-swizzle addresses have bits 6-7
// = 0 from the base (kt*64 occupies them), so
//   swz(base + Dn + kt*64) = swz(base + Dn) ^ (kt*64),
// and with P = swz(base), Q = P ^ 64 (bit-6 handled by XOR, not add):
//   kt=0 -> P+Dn, kt=1 -> Q+Dn, kt=2 -> P+Dn+128, kt=3 -> Q+Dn+128
// (bit 7 of P is 0, so ^128 == +128). Dn (n*4096/8192) and the key bits 9-11
// never interact. All reads are base + compile-time immediates.
static __device__ __forceinline__ unsigned swz(unsigned b) {
    return b ^ (((b >> 9) & 7u) << 4);
}

static __device__ __forceinline__ short f2bf(float f) {
    __bf16 h = (__bf16)f;
    return __builtin_bit_cast(short, h);
}

// cheap silu: v_rcp_f32 instead of the exact-div sequence (~10 instrs)
static __device__ __forceinline__ float silu(float v) {
    return v * __builtin_amdgcn_rcpf(1.f + __expf(-v));
}

// ---- pass 0 (merged prep): weight permute + bias0 + zero-blocks ----
// ws: wd_bf frag-order [5][8ct][8kt][512] (163840 sh) + wstop frag-order
// (16384 sh) + bias0 f32[16][128] at byte 360448.
// blocks 0..703: weights; 704..711: bias0; 712..727: zero out-blocks.
__global__ void prep_kernel(const float* __restrict__ wd,
                            const float* __restrict__ wstop,
                            const float* __restrict__ pe,
                            short* __restrict__ o,
                            float* __restrict__ bias,
                            float* __restrict__ out) {
    int blk = blockIdx.x;
    if (blk < 704) {
        int i = blk * 256 + threadIdx.x;
        if (i < 163840) {
            int s   = i >> 15;
            int r   = i & 32767;
            int ct  = r >> 12;
            int r2  = r & 4095;
            int kt  = r2 >> 9;
            int r3  = r2 & 511;
            int ln  = r3 >> 3;
            int e   = r3 & 7;
            int ch  = ct * 16 + (ln & 15);
            int k   = kt * 32 + (ln >> 4) * 8 + e;
            o[i] = f2bf(wd[((size_t)(s * 128 + ch)) * 256 + k]);
        } else if (i < 180224) {
            int j   = i - 163840;
            int ct  = j >> 11;
            int r2  = j & 2047;
            int kt  = r2 >> 9;
            int r3  = r2 & 511;
            int ln  = r3 >> 3;
            int e   = r3 & 7;
            int ch  = ct * 16 + (ln & 15);
            int k   = kt * 32 + (ln >> 4) * 8 + e;
            o[i] = f2bf(wstop[ch * 128 + k]);
        }
    } else if (blk < 712) {
        int oo = (blk - 704) * 256 + threadIdx.x;   // 0..2047
        int j = oo >> 7;
        int c = oo & 127;
        const float* w  = wd + (size_t)c * 256;
        const float* p0 = pe + (2 * j) * DQ;
        const float* p1 = pe + (2 * j + 1) * DQ;
        float s = 0.f;
        #pragma unroll 4
        for (int i = 0; i < 128; ++i) s += w[i] * p0[i];
        #pragma unroll 4
        for (int i = 0; i < 128; ++i) s += w[i + 128] * p1[i];
        bias[oo] = s;
    } else {
        int i = (blk - 712) * 256 + threadIdx.x;  // 4096 = 32 heads * 128
        int bh = i >> 7, d = i & 127;
        out[(size_t)bh * NBLK * DQ + d] = 0.f;
    }
}

// ---- pass 1: fused compressor, swapped-operand, K-halved wf, sound hoist ----
// Wave = channel-tile ct. A-operand = W frags (16 regs/half), B = activations
// (LDS b128, P/Q base pair + immediate offsets). 36KB LDS, VGPR<=64 ->
// 4 blocks/CU = 32 waves/CU, spill-free.
__global__ __launch_bounds__(512, 8)
void fused_kernel(const float* __restrict__ kin,
                  const short* __restrict__ wdb,
                  const float* __restrict__ bias0,
                  float* __restrict__ out) {
    __shared__ __align__(16) unsigned char lds[36864];

    const int bh = blockIdx.x >> 7;            // 0..31
    const int w0 = (blockIdx.x & 127) * WPB;   // first window of this group
    const int tid  = threadIdx.x;
    const int lane = tid & 63;
    const int ct   = tid >> 6;                 // wave = channel-tile 0..7
    const int kl   = lane >> 4;                // 0..3
    const int nl   = lane & 15;                // 0..15

    const float* kb = kin + (size_t)bh * SQ * DQ;
    const short* wbase = wdb + ct * 4096 + lane * 8;   // per-wave frag base

    // ---- phase A: 80 rows x 16 chunks = 1280 tasks, loaded once ----
    #pragma unroll
    for (int it = 0; it < 3; ++it) {
        int task = tid + it * 512;
        if (task < 1280) {
            int rr = task >> 4;               // 0..79
            int c8 = task & 15;
            int srow = STR * w0 + rr;
            if (srow > SQ - 1) srow = SQ - 1; // clamp (feeds invalid window only)
            const float* kp = kb + (size_t)srow * DQ + c8 * 8;
            f32x4 a0 = *(const f32x4*)kp;
            f32x4 a1 = *(const f32x4*)(kp + 4);
            s16x8 v;
            v[0] = f2bf(a0[0]); v[1] = f2bf(a0[1]); v[2] = f2bf(a0[2]); v[3] = f2bf(a0[3]);
            v[4] = f2bf(a1[0]); v[5] = f2bf(a1[1]); v[6] = f2bf(a1[2]); v[7] = f2bf(a1[3]);
            *(s16x8*)(lds + swz(R_KIN + (unsigned)((rr << 8) + (c8 << 4)))) = v;
        }
    }

    const f32x4 bias = *(const f32x4*)(bias0 + nl * 128 + ct * 16 + kl * 4);
    __syncthreads();   // kin ready

    // 4 b128 reads (P/Q bases + immediates) + 4 MFMAs into accv
#define K_HALF_AT(P, Q, off, accv) {                                           \
        s16x8 aa0 = *(const s16x8*)((P) + (off));                              \
        s16x8 aa1 = *(const s16x8*)((Q) + (off));                              \
        s16x8 aa2 = *(const s16x8*)((P) + (off) + 128);                        \
        s16x8 aa3 = *(const s16x8*)((Q) + (off) + 128);                        \
        accv = __builtin_amdgcn_mfma_f32_16x16x32_bf16(wfh[0], aa0, accv, 0, 0, 0); \
        accv = __builtin_amdgcn_mfma_f32_16x16x32_bf16(wfh[1], aa1, accv, 0, 0, 0); \
        accv = __builtin_amdgcn_mfma_f32_16x16x32_bf16(wfh[2], aa2, accv, 0, 0, 0); \
        accv = __builtin_amdgcn_mfma_f32_16x16x32_bf16(wfh[3], aa3, accv, 0, 0, 0); }

    // ---- stage 0: 4 n-tiles; K=256 in two halves; one P/Q pair per half ----
    {
        f32x4 acc0 = bias, acc1 = bias, acc2 = bias, acc3 = bias;
        #pragma unroll
        for (int half = 0; half < 2; ++half) {
            s16x8 wfh[4];
            #pragma unroll
            for (int kt = 0; kt < 4; ++kt)
                wfh[kt] = *(const s16x8*)(wbase + (half * 4 + kt) * 512);
            unsigned pb = swz(R_KIN + ((unsigned)(2 * nl + half) << 8) + (unsigned)(kl << 4));
            const unsigned char* P = lds + pb;
            const unsigned char* Q = lds + (pb ^ 64u);
            K_HALF_AT(P, Q, 0,     acc0);
            K_HALF_AT(P, Q, 4096,  acc1);
            K_HALF_AT(P, Q, 8192,  acc2);
            K_HALF_AT(P, Q, 12288, acc3);
        }
        #pragma unroll
        for (int n = 0; n < 4; ++n) {
            f32x4 acc = (n == 0) ? acc0 : (n == 1) ? acc1 : (n == 2) ? acc2 : acc3;
            s16x4 v;
            v[0] = f2bf(silu(acc[0])); v[1] = f2bf(silu(acc[1]));
            v[2] = f2bf(silu(acc[2])); v[3] = f2bf(silu(acc[3]));
            unsigned d = (unsigned)(n * 16 + nl);
            *(s16x4*)(lds + swz(R_S0 + (d << 8) + (unsigned)(ct * 32 + kl * 8))) = v;
        }
    }
    __syncthreads();

    // ---- stage 1: 64 in rows -> 32 out rows (2 n-tiles) ----
    {
        f32x4 acc0 = {0.f, 0.f, 0.f, 0.f};
        f32x4 acc1 = {0.f, 0.f, 0.f, 0.f};
        #pragma unroll
        for (int half = 0; half < 2; ++half) {
            s16x8 wfh[4];
            #pragma unroll
            for (int kt = 0; kt < 4; ++kt)
                wfh[kt] = *(const s16x8*)(wbase + 32768 + (half * 4 + kt) * 512);
            unsigned pb = swz(R_S0 + ((unsigned)(2 * nl + half) << 8) + (unsigned)(kl << 4));
            const unsigned char* P = lds + pb;
            const unsigned char* Q = lds + (pb ^ 64u);
            K_HALF_AT(P, Q, 0,    acc0);
            K_HALF_AT(P, Q, 8192, acc1);
        }
        #pragma unroll
        for (int n = 0; n < 2; ++n) {
            f32x4 acc = n ? acc1 : acc0;
            s16x4 v;
            v[0] = f2bf(silu(acc[0])); v[1] = f2bf(silu(acc[1]));
            v[2] = f2bf(silu(acc[2])); v[3] = f2bf(silu(acc[3]));
            unsigned d = (unsigned)(n * 16 + nl);
            *(s16x4*)(lds + swz(R_S1 + (d << 8) + (unsigned)(ct * 32 + kl * 8))) = v;
        }
    }
    __syncthreads();

    // ---- stages 2..4: 1 n-tile each, shrinking valid rows (16,8,4) ----
    const unsigned rin[3]  = {R_S1, R_S2, R_S3};
    const unsigned rout[3] = {R_S2, R_S3, R_S4};
    #pragma unroll
    for (int s = 2; s <= 4; ++s) {
        const int outRows = 32 >> (s - 1);       // 16,8,4
        int d = nl;
        int dc = (d < outRows) ? d : outRows - 1;
        f32x4 acc0 = {0.f, 0.f, 0.f, 0.f};
        #pragma unroll
        for (int half = 0; half < 2; ++half) {
            s16x8 wfh[4];
            #pragma unroll
            for (int kt = 0; kt < 4; ++kt)
                wfh[kt] = *(const s16x8*)(wbase + s * 32768 + (half * 4 + kt) * 512);
            unsigned pb = swz(rin[s - 2] + ((unsigned)(2 * dc + half) << 8) + (unsigned)(kl << 4));
            const unsigned char* P = lds + pb;
            const unsigned char* Q = lds + (pb ^ 64u);
            K_HALF_AT(P, Q, 0, acc0);
        }
        if (d < outRows) {
            s16x4 v;
            v[0] = f2bf(silu(acc0[0])); v[1] = f2bf(silu(acc0[1]));
            v[2] = f2bf(silu(acc0[2])); v[3] = f2bf(silu(acc0[3]));
            *(s16x4*)(lds + swz(rout[s - 2] + ((unsigned)d << 8) + (unsigned)(ct * 32 + kl * 8))) = v;
        }
        __syncthreads();
    }

    // ---- w_stop: input R_S4 [4][256B], K=128, no activation -> global f32 ----
    {
        s16x8 wfh[4];
        #pragma unroll
        for (int kt = 0; kt < 4; ++kt)
            wfh[kt] = *(const s16x8*)(wdb + 163840 + ct * 2048 + kt * 512 + lane * 8);
        int d = nl;
        int dc = (d < WPB) ? d : WPB - 1;
        f32x4 acc = {0.f, 0.f, 0.f, 0.f};
        unsigned pb = swz(R_S4 + ((unsigned)dc << 8) + (unsigned)(kl << 4));
        const unsigned char* P = lds + pb;
        const unsigned char* Q = lds + (pb ^ 64u);
        K_HALF_AT(P, Q, 0, acc);
        int w = w0 + d;
        if (d < WPB && w < NWIN) {
            // lane holds channels ct*16+kl*4 .. +3 of window w: one dwordx4
            *(f32x4*)(out + ((size_t)bh * NBLK + (w + 1)) * DQ + ct * 16 + kl * 4) = acc;
        }
    }
#undef K_HALF_AT
}

extern "C" void kernel_launch(void* const* d_in, const int* in_sizes, int n_in,
                              void* d_out, int out_size, void* d_ws, size_t ws_size,
                              hipStream_t stream) {
    const float* kin   = (const float*)d_in[0];
    const float* pe    = (const float*)d_in[1];
    const float* wdown = (const float*)d_in[2];
    const float* wstop = (const float*)d_in[3];
    float* out = (float*)d_out;
    short* wbf  = (short*)d_ws;                       // 180224 shorts (frag-order)
    float* bias = (float*)((char*)d_ws + 360448);     // f32[2048]

    prep_kernel<<<728, 256, 0, stream>>>(wdown, wstop, pe, wbf, bias, out);
    fused_kernel<<<BQ * HQ * NWG_PER_HEAD, 512, 0, stream>>>(kin, wbf, bias, out);
}